// Round 13
// baseline (333.902 us; speedup 1.0000x reference)
//
#include <hip/hip_runtime.h>

#define N_NODES 100000
#define N_EDGES 1600000
#define NPB 32                       // nodes per bucket (dst >> 5)
#define NB (N_NODES / NPB)           // 3125 buckets
#define CAP 704                      // slots per bucket (mean 512 + 8.5 sigma)
#define NCC 49                       // coarse cells (dst >> 11)
#define CAPA 34816                   // slots per coarse cell (mean 32768 + 11 sigma)
#define NFB 64                       // fine buckets per coarse cell
#define BPC 16                       // blocks per cell in pass B
#define NW0 (N_NODES * 32 / 64)      // 50000 mask words, layer 1
#define NW1 (N_NODES * 64 / 64)      // 100000 mask words, layer 2

typedef float v2f __attribute__((ext_vector_type(2)));

// ---------------- JAX threefry2x32 (partitionable scheme) ----------------
struct U2 { unsigned a, b; };

__host__ __device__ constexpr U2 tf2x32(unsigned k0, unsigned k1, unsigned c0, unsigned c1) {
  unsigned ks2 = k0 ^ k1 ^ 0x1BD11BDAu;
  unsigned x0 = c0 + k0, x1 = c1 + k1;
#define TFR(r) { x0 += x1; x1 = (x1 << (r)) | (x1 >> (32 - (r))); x1 ^= x0; }
  TFR(13) TFR(15) TFR(26) TFR(6)
  x0 += k1;  x1 += ks2 + 1u;
  TFR(17) TFR(29) TFR(16) TFR(24)
  x0 += ks2; x1 += k0 + 2u;
  TFR(13) TFR(15) TFR(26) TFR(6)
  x0 += k0;  x1 += k1 + 3u;
  TFR(17) TFR(29) TFR(16) TFR(24)
  x0 += k1;  x1 += ks2 + 4u;
  TFR(13) TFR(15) TFR(26) TFR(6)
  x0 += ks2; x1 += k0 + 5u;
#undef TFR
  return U2{x0, x1};
}

constexpr U2 DK0 = tf2x32(0u, 42u, 0u, 0u);
constexpr U2 DK1 = tf2x32(0u, 42u, 0u, 1u);

__device__ __forceinline__ bool keep_bit(unsigned k0, unsigned k1, unsigned j) {
  U2 w = tf2x32(k0, k1, 0u, j);
  return ((w.a ^ w.b) >> 31) == 0u;
}

// bf16 storage helpers (RNE pack, shift unpack)
__device__ __forceinline__ unsigned short f2bf(float f) {
  unsigned u = __float_as_uint(f);
  u += 0x7FFFu + ((u >> 16) & 1u);
  return (unsigned short)(u >> 16);
}
// unpack uint32 (2 bf16) -> v2f
__device__ __forceinline__ v2f up2(unsigned r) {
  v2f v;
  v.x = __uint_as_float(r << 16);
  v.y = __uint_as_float(r & 0xFFFF0000u);
  return v;
}

// ------ dropout masks, one ballot word per wave (bit-exact vs inline) ----
__global__ __launch_bounds__(256) void k_mask(
    unsigned long long* __restrict__ m0, unsigned long long* __restrict__ m1) {
  long long gt = (long long)blockIdx.x * 256 + threadIdx.x;
  int w = (int)(gt >> 6), lane = (int)(gt & 63);
  bool keep;
  if (w < NW0) keep = keep_bit(DK0.a, DK0.b, (unsigned)(w * 64 + lane));
  else if (w < NW0 + NW1) keep = keep_bit(DK1.a, DK1.b, (unsigned)((w - NW0) * 64 + lane));
  else return;
  unsigned long long b = __ballot(keep);
  if (lane == 0) {
    if (w < NW0) m0[w] = b;
    else         m1[w - NW0] = b;
  }
}

// ------ Kernel A: xl = bf16(x@W1_l), xr = x@W1_r (wave per row) ----------
__global__ __launch_bounds__(256) void k_transform1(
    const float* __restrict__ x, const float* __restrict__ Wl,
    const float* __restrict__ Wr, unsigned short* __restrict__ xlb,
    float* __restrict__ xr) {
  int wid = (int)((blockIdx.x * blockDim.x + threadIdx.x) >> 6);
  int lane = threadIdx.x & 63;
  if (wid >= N_NODES) return;
  float xv = x[wid * 64 + lane];
  const float* W = (lane < 32) ? Wl : Wr;
  int c = lane & 31;
  float s = 0.f;
#pragma unroll
  for (int k = 0; k < 64; ++k) {
    float b = __shfl(xv, k, 64);
    s += b * W[k * 32 + c];
  }
  if (lane < 32) xlb[wid * 32 + c] = f2bf(s);
  else           xr[wid * 32 + c] = s;
}

// ------ Pass A: LDS-staged partition by coarse cell (dst>>11), 49 cells ---
__global__ __launch_bounds__(256) void k_binA(
    const int* __restrict__ src, const int* __restrict__ dst,
    int* __restrict__ curA, unsigned* __restrict__ bufA) {
  __shared__ int hist[NCC];
  __shared__ int offsL[NCC + 1];
  __shared__ int baseL[NCC];
  __shared__ int place[NCC];
  __shared__ unsigned stag[2048];
  __shared__ unsigned char cellb[2048];
  int t = threadIdx.x;
  for (long long start = (long long)blockIdx.x * 2048; start < N_EDGES;
       start += (long long)gridDim.x * 2048) {
    int n = (int)min((long long)2048, (long long)N_EDGES - start);
    for (int i = t; i < NCC; i += 256) hist[i] = 0;
    __syncthreads();
    unsigned pv[8]; int pc[8];
#pragma unroll
    for (int i = 0; i < 8; ++i) {
      int idx = t + i * 256;
      if (idx < n) {
        int d = dst[start + idx];
        int s = src[start + idx];
        int cc = d >> 11;
        pc[i] = cc;
        pv[i] = (unsigned)s | ((unsigned)(d & 2047) << 17);
        atomicAdd(&hist[cc], 1);
      } else pc[i] = -1;
    }
    __syncthreads();
    if (t < 64) {
      int lane = t;
      int v = (lane < NCC) ? hist[lane] : 0;
      int x = v;
#pragma unroll
      for (int o = 1; o < 64; o <<= 1) {
        int y = __shfl_up(x, o, 64);
        if (lane >= o) x += y;
      }
      if (lane < NCC) {
        offsL[lane] = x - v;
        place[lane] = 0;
        if (v > 0) baseL[lane] = atomicAdd(&curA[lane], v);
      }
      if (lane == NCC - 1) offsL[NCC] = x;
    }
    __syncthreads();
#pragma unroll
    for (int i = 0; i < 8; ++i) {
      if (pc[i] >= 0) {
        int p = atomicAdd(&place[pc[i]], 1);
        int sl = offsL[pc[i]] + p;
        stag[sl] = pv[i];
        cellb[sl] = (unsigned char)pc[i];
      }
    }
    __syncthreads();
    for (int s2 = t; s2 < n; s2 += 256) {     // coalesced copy-out, no search
      int cell = cellb[s2];
      int pos = baseL[cell] + (s2 - offsL[cell]);
      if (pos < CAPA) bufA[(size_t)cell * CAPA + pos] = stag[s2];
    }
    __syncthreads();
  }
}

// ------ Pass B: refine each coarse cell into 64 fine buckets -------------
__global__ __launch_bounds__(256) void k_binB(
    const unsigned* __restrict__ bufA, const int* __restrict__ curA,
    int* __restrict__ cur, unsigned* __restrict__ buf) {
  __shared__ int hist[NFB];
  __shared__ int offsL[NFB + 1];
  __shared__ int baseL[NFB];
  __shared__ int place[NFB];
  __shared__ unsigned stag[2048];
  __shared__ unsigned char cellb[2048];
  int cellc = blockIdx.x / BPC;
  int slice = blockIdx.x % BPC;
  int t = threadIdx.x;
  int cnt = min(curA[cellc], CAPA);
  const unsigned* in = bufA + (size_t)cellc * CAPA;
  for (int start = slice * 2048; start < cnt; start += BPC * 2048) {
    int n = min(2048, cnt - start);
    for (int i = t; i < NFB; i += 256) hist[i] = 0;
    __syncthreads();
    unsigned pv[8]; int pb[8];
#pragma unroll
    for (int i = 0; i < 8; ++i) {
      int idx = t + i * 256;
      if (idx < n) {
        unsigned w = in[start + idx];
        int dlow = (int)(w >> 17);
        int fb = dlow >> 5;
        pb[i] = fb;
        pv[i] = (w & 0x1FFFFu) | ((unsigned)(dlow & 31) << 17);
        atomicAdd(&hist[fb], 1);
      } else pb[i] = -1;
    }
    __syncthreads();
    if (t < 64) {
      int lane = t;
      int v = hist[lane];
      int x = v;
#pragma unroll
      for (int o = 1; o < 64; o <<= 1) {
        int y = __shfl_up(x, o, 64);
        if (lane >= o) x += y;
      }
      offsL[lane] = x - v;
      place[lane] = 0;
      if (v > 0) baseL[lane] = atomicAdd(&cur[cellc * NFB + lane], v);
      if (lane == 63) offsL[NFB] = x;
    }
    __syncthreads();
#pragma unroll
    for (int i = 0; i < 8; ++i) {
      if (pb[i] >= 0) {
        int p = atomicAdd(&place[pb[i]], 1);
        int sl = offsL[pb[i]] + p;
        stag[sl] = pv[i];
        cellb[sl] = (unsigned char)pb[i];
      }
    }
    __syncthreads();
    for (int s2 = t; s2 < n; s2 += 256) {
      int fb = cellb[s2];
      int pos = baseL[fb] + (s2 - offsL[fb]);
      if (pos < CAP) buf[(size_t)(cellc * NFB + fb) * CAP + pos] = stag[s2];
    }
    __syncthreads();
  }
}

// ------ block per bucket: LDS count + prefix, CSR fill to FIXED region ---
// offs = b*CAP + excl (no global scan needed); bucket tile staged in LDS.
__global__ __launch_bounds__(256) void k_bfill(
    const unsigned* __restrict__ buf, const int* __restrict__ cur,
    int* __restrict__ deg, int* __restrict__ offs, int* __restrict__ eidx) {
  __shared__ int ncnt[NPB];
  __shared__ int ncur[NPB];
  __shared__ unsigned sbuf[CAP];
  int b = blockIdx.x, t = threadIdx.x;
  if (t < NPB) ncnt[t] = 0;
  __syncthreads();
  int nb = min(cur[b], CAP);
  const unsigned* bb = buf + (size_t)b * CAP;
  for (int slot = t; slot < nb; slot += 256) {
    unsigned w = bb[slot];
    sbuf[slot] = w;
    atomicAdd(&ncnt[w >> 17], 1);
  }
  __syncthreads();
  if (t < 64) {
    int lane = t;
    int c = (lane < NPB) ? ncnt[lane] : 0;
    int x = c;
#pragma unroll
    for (int o = 1; o < 32; o <<= 1) {
      int y = __shfl_up(x, o, 64);
      if (lane >= o) x += y;
    }
    if (lane < NPB) {
      int excl = x - c;
      ncur[lane] = excl;
      int gn = b * NPB + lane;
      deg[gn] = c;
      offs[gn] = b * CAP + excl;
    }
  }
  __syncthreads();
  int base = b * CAP;
  for (int slot = t; slot < nb; slot += 256) {
    unsigned w = sbuf[slot];
    int p = atomicAdd(&ncur[w >> 17], 1);
    eidx[base + p] = (int)(w & 0x1FFFF);
  }
}

// ---- Gather layer 1: hp = bf16(dropout(lrelu(mean(xl[nbrs])+b1+xr))) ----
__global__ __launch_bounds__(256) void k_gather1(
    const unsigned short* __restrict__ xlb, const float* __restrict__ xr,
    const int* __restrict__ offs, const int* __restrict__ deg,
    const int* __restrict__ eidx, const float* __restrict__ b1,
    const unsigned long long* __restrict__ m0,
    unsigned short* __restrict__ hpb) {
  int wid = (int)((blockIdx.x * blockDim.x + threadIdx.x) >> 6);
  int lane = threadIdx.x & 63;
  if (wid >= N_NODES) return;
  int g = lane >> 3, ch = lane & 7;
  int off = offs[wid];
  int dg = deg[wid];
  const uint2* x2 = (const uint2*)xlb;
  v2f acc01 = {0.f, 0.f}, acc23 = {0.f, 0.f};
  int k = 0;
  for (; k + 16 <= dg; k += 16) {
    int s0 = eidx[off + k + g];
    int s1 = eidx[off + k + 8 + g];
    uint2 r0 = x2[s0 * 8 + ch];
    uint2 r1 = x2[s1 * 8 + ch];
    acc01 += up2(r0.x); acc23 += up2(r0.y);
    acc01 += up2(r1.x); acc23 += up2(r1.y);
  }
  for (; k < dg; k += 8) {
    if (k + g < dg) {
      int s = eidx[off + k + g];
      uint2 r = x2[s * 8 + ch];
      acc01 += up2(r.x); acc23 += up2(r.y);
    }
  }
  float a0 = acc01.x, a1 = acc01.y, a2 = acc23.x, a3 = acc23.y;
  a0 += __shfl_xor(a0, 8, 64); a0 += __shfl_xor(a0, 16, 64); a0 += __shfl_xor(a0, 32, 64);
  a1 += __shfl_xor(a1, 8, 64); a1 += __shfl_xor(a1, 16, 64); a1 += __shfl_xor(a1, 32, 64);
  a2 += __shfl_xor(a2, 8, 64); a2 += __shfl_xor(a2, 16, 64); a2 += __shfl_xor(a2, 32, 64);
  a3 += __shfl_xor(a3, 8, 64); a3 += __shfl_xor(a3, 16, 64); a3 += __shfl_xor(a3, 32, 64);
  int chunk = lane >> 2, sub = lane & 3;
  float t0 = __shfl(a0, chunk, 64);
  float t1 = __shfl(a1, chunk, 64);
  float t2 = __shfl(a2, chunk, 64);
  float t3 = __shfl(a3, chunk, 64);
  float val = (sub == 0) ? t0 : (sub == 1) ? t1 : (sub == 2) ? t2 : t3;
  if (lane < 32) {
    unsigned long long mw = m0[wid >> 1];          // broadcast 8B load
    float inv = 1.0f / fmaxf((float)dg, 1.0f);
    int j = wid * 32 + lane;
    float v = val * inv + b1[lane] + xr[j];
    v = (v > 0.f) ? v : 0.01f * v;
    bool keep = (mw >> ((wid & 1) * 32 + lane)) & 1ull;
    hpb[j] = f2bf(keep ? 2.0f * v : 0.0f);
  }
}

// ---- Gather layer 2 + LDS-broadcast GEMM (pk_fma) + dropout + L2 norm ---
__global__ __launch_bounds__(256) void k_out(
    const unsigned short* __restrict__ hpb, const int* __restrict__ offs,
    const int* __restrict__ deg, const int* __restrict__ eidx,
    const float* __restrict__ W2l, const float* __restrict__ b2,
    const float* __restrict__ W2r, const unsigned long long* __restrict__ m1,
    float* __restrict__ out) {
  __shared__ __align__(16) float rv[4][64];
  int wid = (int)((blockIdx.x * blockDim.x + threadIdx.x) >> 6);
  int lane = threadIdx.x & 63;
  int wv = (threadIdx.x >> 6) & 3;
  if (wid >= N_NODES) return;
  int g = lane >> 3, ch = lane & 7;
  int off = offs[wid];
  int dg = deg[wid];
  const uint2* h2 = (const uint2*)hpb;
  v2f acc01 = {0.f, 0.f}, acc23 = {0.f, 0.f};
  int k = 0;
  for (; k + 16 <= dg; k += 16) {
    int s0 = eidx[off + k + g];
    int s1 = eidx[off + k + 8 + g];
    uint2 r0 = h2[s0 * 8 + ch];
    uint2 r1 = h2[s1 * 8 + ch];
    acc01 += up2(r0.x); acc23 += up2(r0.y);
    acc01 += up2(r1.x); acc23 += up2(r1.y);
  }
  for (; k < dg; k += 8) {
    if (k + g < dg) {
      int s = eidx[off + k + g];
      uint2 r = h2[s * 8 + ch];
      acc01 += up2(r.x); acc23 += up2(r.y);
    }
  }
  float a0 = acc01.x, a1 = acc01.y, a2 = acc23.x, a3 = acc23.y;
  a0 += __shfl_xor(a0, 8, 64); a0 += __shfl_xor(a0, 16, 64); a0 += __shfl_xor(a0, 32, 64);
  a1 += __shfl_xor(a1, 8, 64); a1 += __shfl_xor(a1, 16, 64); a1 += __shfl_xor(a1, 32, 64);
  a2 += __shfl_xor(a2, 8, 64); a2 += __shfl_xor(a2, 16, 64); a2 += __shfl_xor(a2, 32, 64);
  a3 += __shfl_xor(a3, 8, 64); a3 += __shfl_xor(a3, 16, 64); a3 += __shfl_xor(a3, 32, 64);
  float inv = 1.0f / fmaxf((float)dg, 1.0f);
  if (lane < 8) {                     // mean-agg row, cols 4*lane..4*lane+3
    float4 v;
    v.x = a0 * inv; v.y = a1 * inv; v.z = a2 * inv; v.w = a3 * inv;
    *(float4*)&rv[wv][lane * 4] = v;
  } else if (lane < 16) {             // own hp row, cols 32+4*(lane-8)..
    uint2 r = h2[wid * 8 + (lane - 8)];
    float4 v;
    v.x = __uint_as_float(r.x << 16);
    v.y = __uint_as_float(r.x & 0xFFFF0000u);
    v.z = __uint_as_float(r.y << 16);
    v.w = __uint_as_float(r.y & 0xFFFF0000u);
    *(float4*)&rv[wv][32 + (lane - 8) * 4] = v;
  }
  asm volatile("s_waitcnt lgkmcnt(0)" ::: "memory");   // same-wave LDS drain
  v2f sa = {0.f, 0.f}, sb = {0.f, 0.f};
#pragma unroll
  for (int kk = 0; kk < 32; kk += 4) {
    float4 r1 = *(const float4*)&rv[wv][kk];
    float4 r2 = *(const float4*)&rv[wv][32 + kk];
    v2f w0; w0.x = W2l[(kk + 0) * 64 + lane]; w0.y = W2l[(kk + 1) * 64 + lane];
    v2f w1; w1.x = W2l[(kk + 2) * 64 + lane]; w1.y = W2l[(kk + 3) * 64 + lane];
    v2f u0; u0.x = W2r[(kk + 0) * 64 + lane]; u0.y = W2r[(kk + 1) * 64 + lane];
    v2f u1; u1.x = W2r[(kk + 2) * 64 + lane]; u1.y = W2r[(kk + 3) * 64 + lane];
    v2f p0; p0.x = r1.x; p0.y = r1.y;
    v2f p1; p1.x = r1.z; p1.y = r1.w;
    v2f q0; q0.x = r2.x; q0.y = r2.y;
    v2f q1; q1.x = r2.z; q1.y = r2.w;
    sa += p0 * w0;  sa += p1 * w1;    // v_pk_fma_f32
    sb += q0 * u0;  sb += q1 * u1;
  }
  float v = (sa.x + sa.y) + (sb.x + sb.y) + b2[lane];
  unsigned long long mw = m1[wid];                     // broadcast 8B load
  float d = ((mw >> lane) & 1ull) ? 2.0f * v : 0.0f;
  float ss = d * d;
#pragma unroll
  for (int o = 32; o > 0; o >>= 1) ss += __shfl_xor(ss, o, 64);
  float scale = 1.0f / fmaxf(sqrtf(ss), 1e-12f);
  out[wid * 64 + lane] = d * scale;
}

// --------------------------------------------------------------------------
extern "C" void kernel_launch(void* const* d_in, const int* in_sizes, int n_in,
                              void* d_out, int out_size, void* d_ws, size_t ws_size,
                              hipStream_t stream) {
  const float* x   = (const float*)d_in[0];
  const int*   ei  = (const int*)d_in[1];
  const float* W1l = (const float*)d_in[2];
  const float* b1  = (const float*)d_in[3];
  const float* W1r = (const float*)d_in[4];
  const float* W2l = (const float*)d_in[5];
  const float* b2  = (const float*)d_in[6];
  const float* W2r = (const float*)d_in[7];
  float* out = (float*)d_out;

  const int* src = ei;            // edge_index[0]
  const int* dst = ei + N_EDGES;  // edge_index[1]

  const size_t F32 = (size_t)N_NODES * 32;
  char* w = (char*)d_ws;
  // region 1 (12.8 MB): bufA (passes A/B) then xr (transform onward)
  unsigned* bufA = (unsigned*)w;                 // 49*34816*4 = 6.8 MB
  float* xr      = (float*)w;                    // 12.8 MB (bufA dead by then)
  w += F32 * sizeof(float);
  // region 2 (12.8 MB): buf (passes B/bfill) then xlb+hpb (transform onward)
  unsigned* buf  = (unsigned*)w;                 // 3125*704*4 = 8.8 MB
  unsigned short* xlb = (unsigned short*)w;      // 6.4 MB
  unsigned short* hpb = xlb + F32;               // 6.4 MB (buf dead by then)
  w += F32 * 2 * sizeof(unsigned short);
  int* curA  = (int*)w; w += NCC * sizeof(int);
  int* cur   = (int*)w; w += NB * sizeof(int);
  int* deg   = (int*)w; w += N_NODES * sizeof(int);
  int* offs  = (int*)w; w += N_NODES * sizeof(int);
  int* eidx  = (int*)w; w += (size_t)NB * CAP * sizeof(int);   // 8.8 MB
  unsigned long long* m0 = (unsigned long long*)w; w += NW0 * 8; // 400 KB
  unsigned long long* m1 = (unsigned long long*)w;               // 800 KB

  hipMemsetAsync(curA, 0, (size_t)(NCC + NB) * sizeof(int), stream);

  k_mask<<<((NW0 + NW1) * 64 + 255) / 256, 256, 0, stream>>>(m0, m1);
  k_binA<<<(N_EDGES + 2047) / 2048, 256, 0, stream>>>(src, dst, curA, bufA);
  k_binB<<<NCC * BPC, 256, 0, stream>>>(bufA, curA, cur, buf);
  k_bfill<<<NB, 256, 0, stream>>>(buf, cur, deg, offs, eidx);

  k_transform1<<<(N_NODES + 3) / 4, 256, 0, stream>>>(x, W1l, W1r, xlb, xr);
  k_gather1<<<(N_NODES + 3) / 4, 256, 0, stream>>>(xlb, xr, offs, deg, eidx, b1, m0, hpb);
  k_out<<<(N_NODES + 3) / 4, 256, 0, stream>>>(hpb, offs, deg, eidx, W2l, b2, W2r, m1, out);
}

// Round 14
// 312.442 us; speedup vs baseline: 1.0687x; 1.0687x over previous
//
#include <hip/hip_runtime.h>

#define N_NODES 100000
#define N_EDGES 1600000
#define NPB 32                       // nodes per bucket (dst >> 5)
#define NB (N_NODES / NPB)           // 3125 buckets
#define CAP 704                      // slots per bucket (mean 512 + 8.5 sigma)
#define NCC 49                       // coarse cells (dst >> 11)
#define CAPA 34816                   // slots per coarse cell (mean 32768 + 11 sigma)
#define NFB 64                       // fine buckets per coarse cell
#define BPC 16                       // blocks per cell in pass B

typedef float v2f __attribute__((ext_vector_type(2)));

// ---------------- JAX threefry2x32 (partitionable scheme) ----------------
struct U2 { unsigned a, b; };

__host__ __device__ constexpr U2 tf2x32(unsigned k0, unsigned k1, unsigned c0, unsigned c1) {
  unsigned ks2 = k0 ^ k1 ^ 0x1BD11BDAu;
  unsigned x0 = c0 + k0, x1 = c1 + k1;
#define TFR(r) { x0 += x1; x1 = (x1 << (r)) | (x1 >> (32 - (r))); x1 ^= x0; }
  TFR(13) TFR(15) TFR(26) TFR(6)
  x0 += k1;  x1 += ks2 + 1u;
  TFR(17) TFR(29) TFR(16) TFR(24)
  x0 += ks2; x1 += k0 + 2u;
  TFR(13) TFR(15) TFR(26) TFR(6)
  x0 += k0;  x1 += k1 + 3u;
  TFR(17) TFR(29) TFR(16) TFR(24)
  x0 += k1;  x1 += ks2 + 4u;
  TFR(13) TFR(15) TFR(26) TFR(6)
  x0 += ks2; x1 += k0 + 5u;
#undef TFR
  return U2{x0, x1};
}

constexpr U2 DK0 = tf2x32(0u, 42u, 0u, 0u);
constexpr U2 DK1 = tf2x32(0u, 42u, 0u, 1u);

__device__ __forceinline__ bool keep_bit(unsigned k0, unsigned k1, unsigned j) {
  U2 w = tf2x32(k0, k1, 0u, j);
  return ((w.a ^ w.b) >> 31) == 0u;
}

// bf16 storage helpers (RNE pack, shift unpack)
__device__ __forceinline__ unsigned short f2bf(float f) {
  unsigned u = __float_as_uint(f);
  u += 0x7FFFu + ((u >> 16) & 1u);
  return (unsigned short)(u >> 16);
}
// unpack uint32 (2 bf16) -> v2f
__device__ __forceinline__ v2f up2(unsigned r) {
  v2f v;
  v.x = __uint_as_float(r << 16);
  v.y = __uint_as_float(r & 0xFFFF0000u);
  return v;
}

// ------ Kernel A: xl = bf16(x@W1_l), xr = x@W1_r (wave per row) ----------
__global__ __launch_bounds__(256) void k_transform1(
    const float* __restrict__ x, const float* __restrict__ Wl,
    const float* __restrict__ Wr, unsigned short* __restrict__ xlb,
    float* __restrict__ xr) {
  int wid = (int)((blockIdx.x * blockDim.x + threadIdx.x) >> 6);
  int lane = threadIdx.x & 63;
  if (wid >= N_NODES) return;
  float xv = x[wid * 64 + lane];
  const float* W = (lane < 32) ? Wl : Wr;
  int c = lane & 31;
  float s = 0.f;
#pragma unroll
  for (int k = 0; k < 64; ++k) {
    float b = __shfl(xv, k, 64);
    s += b * W[k * 32 + c];
  }
  if (lane < 32) xlb[wid * 32 + c] = f2bf(s);
  else           xr[wid * 32 + c] = s;
}

// ------ Pass A: LDS-staged partition by coarse cell (dst>>11), 49 cells ---
__global__ __launch_bounds__(256) void k_binA(
    const int* __restrict__ src, const int* __restrict__ dst,
    int* __restrict__ curA, unsigned* __restrict__ bufA) {
  __shared__ int hist[NCC];
  __shared__ int offsL[NCC + 1];
  __shared__ int baseL[NCC];
  __shared__ int place[NCC];
  __shared__ unsigned stag[2048];
  __shared__ unsigned char cellb[2048];
  int t = threadIdx.x;
  for (long long start = (long long)blockIdx.x * 2048; start < N_EDGES;
       start += (long long)gridDim.x * 2048) {
    int n = (int)min((long long)2048, (long long)N_EDGES - start);
    for (int i = t; i < NCC; i += 256) hist[i] = 0;
    __syncthreads();
    unsigned pv[8]; int pc[8];
#pragma unroll
    for (int i = 0; i < 8; ++i) {
      int idx = t + i * 256;
      if (idx < n) {
        int d = dst[start + idx];
        int s = src[start + idx];
        int cc = d >> 11;
        pc[i] = cc;
        pv[i] = (unsigned)s | ((unsigned)(d & 2047) << 17);
        atomicAdd(&hist[cc], 1);
      } else pc[i] = -1;
    }
    __syncthreads();
    if (t < 64) {
      int lane = t;
      int v = (lane < NCC) ? hist[lane] : 0;
      int x = v;
#pragma unroll
      for (int o = 1; o < 64; o <<= 1) {
        int y = __shfl_up(x, o, 64);
        if (lane >= o) x += y;
      }
      if (lane < NCC) {
        offsL[lane] = x - v;
        place[lane] = 0;
        if (v > 0) baseL[lane] = atomicAdd(&curA[lane], v);
      }
      if (lane == NCC - 1) offsL[NCC] = x;
    }
    __syncthreads();
#pragma unroll
    for (int i = 0; i < 8; ++i) {
      if (pc[i] >= 0) {
        int p = atomicAdd(&place[pc[i]], 1);
        int sl = offsL[pc[i]] + p;
        stag[sl] = pv[i];
        cellb[sl] = (unsigned char)pc[i];
      }
    }
    __syncthreads();
    for (int s2 = t; s2 < n; s2 += 256) {     // coalesced copy-out, no search
      int cell = cellb[s2];
      int pos = baseL[cell] + (s2 - offsL[cell]);
      if (pos < CAPA) bufA[(size_t)cell * CAPA + pos] = stag[s2];
    }
    __syncthreads();
  }
}

// ------ Pass B: refine each coarse cell into 64 fine buckets -------------
__global__ __launch_bounds__(256) void k_binB(
    const unsigned* __restrict__ bufA, const int* __restrict__ curA,
    int* __restrict__ cur, unsigned* __restrict__ buf) {
  __shared__ int hist[NFB];
  __shared__ int offsL[NFB + 1];
  __shared__ int baseL[NFB];
  __shared__ int place[NFB];
  __shared__ unsigned stag[2048];
  __shared__ unsigned char cellb[2048];
  int cellc = blockIdx.x / BPC;
  int slice = blockIdx.x % BPC;
  int t = threadIdx.x;
  int cnt = min(curA[cellc], CAPA);
  const unsigned* in = bufA + (size_t)cellc * CAPA;
  for (int start = slice * 2048; start < cnt; start += BPC * 2048) {
    int n = min(2048, cnt - start);
    for (int i = t; i < NFB; i += 256) hist[i] = 0;
    __syncthreads();
    unsigned pv[8]; int pb[8];
#pragma unroll
    for (int i = 0; i < 8; ++i) {
      int idx = t + i * 256;
      if (idx < n) {
        unsigned w = in[start + idx];
        int dlow = (int)(w >> 17);
        int fb = dlow >> 5;
        pb[i] = fb;
        pv[i] = (w & 0x1FFFFu) | ((unsigned)(dlow & 31) << 17);
        atomicAdd(&hist[fb], 1);
      } else pb[i] = -1;
    }
    __syncthreads();
    if (t < 64) {
      int lane = t;
      int v = hist[lane];
      int x = v;
#pragma unroll
      for (int o = 1; o < 64; o <<= 1) {
        int y = __shfl_up(x, o, 64);
        if (lane >= o) x += y;
      }
      offsL[lane] = x - v;
      place[lane] = 0;
      if (v > 0) baseL[lane] = atomicAdd(&cur[cellc * NFB + lane], v);
      if (lane == 63) offsL[NFB] = x;
    }
    __syncthreads();
#pragma unroll
    for (int i = 0; i < 8; ++i) {
      if (pb[i] >= 0) {
        int p = atomicAdd(&place[pb[i]], 1);
        int sl = offsL[pb[i]] + p;
        stag[sl] = pv[i];
        cellb[sl] = (unsigned char)pb[i];
      }
    }
    __syncthreads();
    for (int s2 = t; s2 < n; s2 += 256) {
      int fb = cellb[s2];
      int pos = baseL[fb] + (s2 - offsL[fb]);
      if (pos < CAP) buf[(size_t)(cellc * NFB + fb) * CAP + pos] = stag[s2];
    }
    __syncthreads();
  }
}

// --------- single-block exclusive scan of bucket totals -> bbase ----------
__global__ __launch_bounds__(1024) void k_bscan(
    const int* __restrict__ cur, int* __restrict__ bbase) {
  __shared__ int warp_sums[16];
  __shared__ int s_running;
  int t = threadIdx.x;
  int lane = t & 63, w = t >> 6;
  if (t == 0) s_running = 0;
  __syncthreads();
  for (int base = 0; base < NB; base += 1024) {
    int i = base + t;
    int v = (i < NB) ? min(cur[i], CAP) : 0;
    int x = v;
#pragma unroll
    for (int o = 1; o < 64; o <<= 1) {
      int y = __shfl_up(x, o, 64);
      if (lane >= o) x += y;
    }
    if (lane == 63) warp_sums[w] = x;
    __syncthreads();
    if (w == 0) {
      int ws = (lane < 16) ? warp_sums[lane] : 0;
#pragma unroll
      for (int o = 1; o < 16; o <<= 1) {
        int y = __shfl_up(ws, o, 64);
        if (lane >= o) ws += y;
      }
      if (lane < 16) warp_sums[lane] = ws;
    }
    __syncthreads();
    int incl = x + (w > 0 ? warp_sums[w - 1] : 0);
    int excl = s_running + incl - v;
    if (i < NB) bbase[i] = excl;
    __syncthreads();
    if (t == 1023) s_running += incl;
    __syncthreads();
  }
}

// ------ block per bucket: LDS-staged count + prefix, dense CSR fill -------
__global__ __launch_bounds__(256) void k_bfill(
    const unsigned* __restrict__ buf, const int* __restrict__ cur,
    const int* __restrict__ bbase, int* __restrict__ deg,
    int* __restrict__ offs, int* __restrict__ eidx) {
  __shared__ int ncnt[NPB];
  __shared__ int ncur[NPB];
  __shared__ unsigned sbuf[CAP];
  int b = blockIdx.x, t = threadIdx.x;
  if (t < NPB) ncnt[t] = 0;
  __syncthreads();
  int nb = min(cur[b], CAP);
  const unsigned* bb = buf + (size_t)b * CAP;
  for (int slot = t; slot < nb; slot += 256) {
    unsigned w = bb[slot];
    sbuf[slot] = w;
    atomicAdd(&ncnt[w >> 17], 1);
  }
  __syncthreads();
  if (t < 64) {
    int lane = t;
    int c = (lane < NPB) ? ncnt[lane] : 0;
    int x = c;
#pragma unroll
    for (int o = 1; o < 32; o <<= 1) {
      int y = __shfl_up(x, o, 64);
      if (lane >= o) x += y;
    }
    if (lane < NPB) {
      int excl = x - c;
      ncur[lane] = excl;
      int gn = b * NPB + lane;
      deg[gn] = c;
      offs[gn] = bbase[b] + excl;
    }
  }
  __syncthreads();
  int base = bbase[b];
  for (int slot = t; slot < nb; slot += 256) {
    unsigned w = sbuf[slot];
    int p = atomicAdd(&ncur[w >> 17], 1);
    eidx[base + p] = (int)(w & 0x1FFFF);
  }
}

// ---- Gather layer 1: hp = bf16(dropout(lrelu(mean(xl[nbrs])+b1+xr))) ----
__global__ __launch_bounds__(256) void k_gather1(
    const unsigned short* __restrict__ xlb, const float* __restrict__ xr,
    const int* __restrict__ offs, const int* __restrict__ deg,
    const int* __restrict__ eidx, const float* __restrict__ b1,
    unsigned short* __restrict__ hpb) {
  int wid = (int)((blockIdx.x * blockDim.x + threadIdx.x) >> 6);
  int lane = threadIdx.x & 63;
  if (wid >= N_NODES) return;
  int g = lane >> 3, ch = lane & 7;
  int off = offs[wid];
  int dg = deg[wid];
  // hoisted tail operands: in flight during the gather loop
  int c32 = lane & 31;
  float xr_v = xr[wid * 32 + c32];
  float b1_v = b1[c32];
  const uint2* x2 = (const uint2*)xlb;
  v2f acc01 = {0.f, 0.f}, acc23 = {0.f, 0.f};
  int k = 0;
  for (; k + 16 <= dg; k += 16) {
    int s0 = eidx[off + k + g];
    int s1 = eidx[off + k + 8 + g];
    uint2 r0 = x2[s0 * 8 + ch];
    uint2 r1 = x2[s1 * 8 + ch];
    acc01 += up2(r0.x); acc23 += up2(r0.y);
    acc01 += up2(r1.x); acc23 += up2(r1.y);
  }
  for (; k < dg; k += 8) {
    if (k + g < dg) {
      int s = eidx[off + k + g];
      uint2 r = x2[s * 8 + ch];
      acc01 += up2(r.x); acc23 += up2(r.y);
    }
  }
  float a0 = acc01.x, a1 = acc01.y, a2 = acc23.x, a3 = acc23.y;
  a0 += __shfl_xor(a0, 8, 64); a0 += __shfl_xor(a0, 16, 64); a0 += __shfl_xor(a0, 32, 64);
  a1 += __shfl_xor(a1, 8, 64); a1 += __shfl_xor(a1, 16, 64); a1 += __shfl_xor(a1, 32, 64);
  a2 += __shfl_xor(a2, 8, 64); a2 += __shfl_xor(a2, 16, 64); a2 += __shfl_xor(a2, 32, 64);
  a3 += __shfl_xor(a3, 8, 64); a3 += __shfl_xor(a3, 16, 64); a3 += __shfl_xor(a3, 32, 64);
  int chunk = lane >> 2, sub = lane & 3;
  float t0 = __shfl(a0, chunk, 64);
  float t1 = __shfl(a1, chunk, 64);
  float t2 = __shfl(a2, chunk, 64);
  float t3 = __shfl(a3, chunk, 64);
  float val = (sub == 0) ? t0 : (sub == 1) ? t1 : (sub == 2) ? t2 : t3;
  if (lane < 32) {
    float inv = 1.0f / fmaxf((float)dg, 1.0f);
    int j = wid * 32 + lane;
    float v = val * inv + b1_v + xr_v;
    v = (v > 0.f) ? v : 0.01f * v;
    float h = keep_bit(DK0.a, DK0.b, (unsigned)j) ? 2.0f * v : 0.0f;
    hpb[j] = f2bf(h);
  }
}

// ---- Gather layer 2 + LDS-broadcast GEMM (pk_fma) + dropout + L2 norm ---
__global__ __launch_bounds__(256) void k_out(
    const unsigned short* __restrict__ hpb, const int* __restrict__ offs,
    const int* __restrict__ deg, const int* __restrict__ eidx,
    const float* __restrict__ W2l, const float* __restrict__ b2,
    const float* __restrict__ W2r, float* __restrict__ out) {
  __shared__ __align__(16) float rv[4][64];
  int wid = (int)((blockIdx.x * blockDim.x + threadIdx.x) >> 6);
  int lane = threadIdx.x & 63;
  int wv = (threadIdx.x >> 6) & 3;
  if (wid >= N_NODES) return;
  int g = lane >> 3, ch = lane & 7;
  int off = offs[wid];
  int dg = deg[wid];
  const uint2* h2 = (const uint2*)hpb;
  // hoisted: own hp-row chunk (one 64B line/wave) + bias, in flight during gather
  uint2 own = h2[wid * 8 + ch];
  float bias = b2[lane];
  v2f acc01 = {0.f, 0.f}, acc23 = {0.f, 0.f};
  int k = 0;
  for (; k + 16 <= dg; k += 16) {
    int s0 = eidx[off + k + g];
    int s1 = eidx[off + k + 8 + g];
    uint2 r0 = h2[s0 * 8 + ch];
    uint2 r1 = h2[s1 * 8 + ch];
    acc01 += up2(r0.x); acc23 += up2(r0.y);
    acc01 += up2(r1.x); acc23 += up2(r1.y);
  }
  for (; k < dg; k += 8) {
    if (k + g < dg) {
      int s = eidx[off + k + g];
      uint2 r = h2[s * 8 + ch];
      acc01 += up2(r.x); acc23 += up2(r.y);
    }
  }
  float a0 = acc01.x, a1 = acc01.y, a2 = acc23.x, a3 = acc23.y;
  a0 += __shfl_xor(a0, 8, 64); a0 += __shfl_xor(a0, 16, 64); a0 += __shfl_xor(a0, 32, 64);
  a1 += __shfl_xor(a1, 8, 64); a1 += __shfl_xor(a1, 16, 64); a1 += __shfl_xor(a1, 32, 64);
  a2 += __shfl_xor(a2, 8, 64); a2 += __shfl_xor(a2, 16, 64); a2 += __shfl_xor(a2, 32, 64);
  a3 += __shfl_xor(a3, 8, 64); a3 += __shfl_xor(a3, 16, 64); a3 += __shfl_xor(a3, 32, 64);
  float inv = 1.0f / fmaxf((float)dg, 1.0f);
  if (lane < 8) {                     // mean-agg row, cols 4*lane..4*lane+3
    float4 v;
    v.x = a0 * inv; v.y = a1 * inv; v.z = a2 * inv; v.w = a3 * inv;
    *(float4*)&rv[wv][lane * 4] = v;
  } else if (lane < 16) {             // own hp row (ch == lane-8 here)
    float4 v;
    v.x = __uint_as_float(own.x << 16);
    v.y = __uint_as_float(own.x & 0xFFFF0000u);
    v.z = __uint_as_float(own.y << 16);
    v.w = __uint_as_float(own.y & 0xFFFF0000u);
    *(float4*)&rv[wv][32 + (lane - 8) * 4] = v;
  }
  asm volatile("s_waitcnt lgkmcnt(0)" ::: "memory");   // same-wave LDS drain
  v2f sa = {0.f, 0.f}, sb = {0.f, 0.f};
#pragma unroll
  for (int kk = 0; kk < 32; kk += 4) {
    float4 r1 = *(const float4*)&rv[wv][kk];
    float4 r2 = *(const float4*)&rv[wv][32 + kk];
    v2f w0; w0.x = W2l[(kk + 0) * 64 + lane]; w0.y = W2l[(kk + 1) * 64 + lane];
    v2f w1; w1.x = W2l[(kk + 2) * 64 + lane]; w1.y = W2l[(kk + 3) * 64 + lane];
    v2f u0; u0.x = W2r[(kk + 0) * 64 + lane]; u0.y = W2r[(kk + 1) * 64 + lane];
    v2f u1; u1.x = W2r[(kk + 2) * 64 + lane]; u1.y = W2r[(kk + 3) * 64 + lane];
    v2f p0; p0.x = r1.x; p0.y = r1.y;
    v2f p1; p1.x = r1.z; p1.y = r1.w;
    v2f q0; q0.x = r2.x; q0.y = r2.y;
    v2f q1; q1.x = r2.z; q1.y = r2.w;
    sa += p0 * w0;  sa += p1 * w1;    // v_pk_fma_f32
    sb += q0 * u0;  sb += q1 * u1;
  }
  float v = (sa.x + sa.y) + (sb.x + sb.y) + bias;
  unsigned j = (unsigned)(wid * 64 + lane);
  float d = keep_bit(DK1.a, DK1.b, j) ? 2.0f * v : 0.0f;
  float ss = d * d;
#pragma unroll
  for (int o = 32; o > 0; o >>= 1) ss += __shfl_xor(ss, o, 64);
  float scale = 1.0f / fmaxf(sqrtf(ss), 1e-12f);
  out[j] = d * scale;
}

// --------------------------------------------------------------------------
extern "C" void kernel_launch(void* const* d_in, const int* in_sizes, int n_in,
                              void* d_out, int out_size, void* d_ws, size_t ws_size,
                              hipStream_t stream) {
  const float* x   = (const float*)d_in[0];
  const int*   ei  = (const int*)d_in[1];
  const float* W1l = (const float*)d_in[2];
  const float* b1  = (const float*)d_in[3];
  const float* W1r = (const float*)d_in[4];
  const float* W2l = (const float*)d_in[5];
  const float* b2  = (const float*)d_in[6];
  const float* W2r = (const float*)d_in[7];
  float* out = (float*)d_out;

  const int* src = ei;            // edge_index[0]
  const int* dst = ei + N_EDGES;  // edge_index[1]

  const size_t F32 = (size_t)N_NODES * 32;
  char* w = (char*)d_ws;
  // region 1 (12.8 MB): bufA (passes A/B) then xr (transform onward)
  unsigned* bufA = (unsigned*)w;                 // 49*34816*4 = 6.8 MB
  float* xr      = (float*)w;                    // 12.8 MB (bufA dead by then)
  w += F32 * sizeof(float);
  // region 2 (12.8 MB): buf (passes B/bfill) then xlb+hpb (transform onward)
  unsigned* buf  = (unsigned*)w;                 // 3125*704*4 = 8.8 MB
  unsigned short* xlb = (unsigned short*)w;      // 6.4 MB
  unsigned short* hpb = xlb + F32;               // 6.4 MB (buf dead by then)
  w += F32 * 2 * sizeof(unsigned short);
  int* curA  = (int*)w; w += NCC * sizeof(int);
  int* cur   = (int*)w; w += NB * sizeof(int);
  int* bbase = (int*)w; w += NB * sizeof(int);
  int* deg   = (int*)w; w += N_NODES * sizeof(int);
  int* offs  = (int*)w; w += N_NODES * sizeof(int);
  int* eidx  = (int*)w;                          // 6.4 MB (dense)

  hipMemsetAsync(curA, 0, (size_t)(NCC + NB) * sizeof(int), stream);

  k_binA<<<(N_EDGES + 2047) / 2048, 256, 0, stream>>>(src, dst, curA, bufA);
  k_binB<<<NCC * BPC, 256, 0, stream>>>(bufA, curA, cur, buf);
  k_bscan<<<1, 1024, 0, stream>>>(cur, bbase);
  k_bfill<<<NB, 256, 0, stream>>>(buf, cur, bbase, deg, offs, eidx);

  k_transform1<<<(N_NODES + 3) / 4, 256, 0, stream>>>(x, W1l, W1r, xlb, xr);
  k_gather1<<<(N_NODES + 3) / 4, 256, 0, stream>>>(xlb, xr, offs, deg, eidx, b1, hpb);
  k_out<<<(N_NODES + 3) / 4, 256, 0, stream>>>(hpb, offs, deg, eidx, W2l, b2, W2r, out);
}

// Round 15
// 294.950 us; speedup vs baseline: 1.1321x; 1.0593x over previous
//
#include <hip/hip_runtime.h>

#define N_NODES 100000
#define N_EDGES 1600000
#define NPB 32                       // nodes per bucket (dst >> 5)
#define NB (N_NODES / NPB)           // 3125 buckets
#define CAP 704                      // slots per bucket (mean 512 + 8.5 sigma)
#define NCC 49                       // coarse cells (dst >> 11)
#define CAPA 34816                   // slots per coarse cell (mean 32768 + 11 sigma)
#define NFB 64                       // fine buckets per coarse cell
#define BPC 16                       // blocks per cell in pass B

typedef float v2f __attribute__((ext_vector_type(2)));

// ---------------- JAX threefry2x32 (partitionable scheme) ----------------
struct U2 { unsigned a, b; };

__host__ __device__ constexpr U2 tf2x32(unsigned k0, unsigned k1, unsigned c0, unsigned c1) {
  unsigned ks2 = k0 ^ k1 ^ 0x1BD11BDAu;
  unsigned x0 = c0 + k0, x1 = c1 + k1;
#define TFR(r) { x0 += x1; x1 = (x1 << (r)) | (x1 >> (32 - (r))); x1 ^= x0; }
  TFR(13) TFR(15) TFR(26) TFR(6)
  x0 += k1;  x1 += ks2 + 1u;
  TFR(17) TFR(29) TFR(16) TFR(24)
  x0 += ks2; x1 += k0 + 2u;
  TFR(13) TFR(15) TFR(26) TFR(6)
  x0 += k0;  x1 += k1 + 3u;
  TFR(17) TFR(29) TFR(16) TFR(24)
  x0 += k1;  x1 += ks2 + 4u;
  TFR(13) TFR(15) TFR(26) TFR(6)
  x0 += ks2; x1 += k0 + 5u;
#undef TFR
  return U2{x0, x1};
}

constexpr U2 DK0 = tf2x32(0u, 42u, 0u, 0u);
constexpr U2 DK1 = tf2x32(0u, 42u, 0u, 1u);

__device__ __forceinline__ bool keep_bit(unsigned k0, unsigned k1, unsigned j) {
  U2 w = tf2x32(k0, k1, 0u, j);
  return ((w.a ^ w.b) >> 31) == 0u;
}

// bf16 storage helpers (RNE pack, shift unpack)
__device__ __forceinline__ unsigned short f2bf(float f) {
  unsigned u = __float_as_uint(f);
  u += 0x7FFFu + ((u >> 16) & 1u);
  return (unsigned short)(u >> 16);
}
// unpack uint32 (2 bf16) -> v2f
__device__ __forceinline__ v2f up2(unsigned r) {
  v2f v;
  v.x = __uint_as_float(r << 16);
  v.y = __uint_as_float(r & 0xFFFF0000u);
  return v;
}

// ------ Kernel A: xl = bf16(x@W1_l), xr = x@W1_r ------------------------
// LDS-broadcast GEMM (k_out-epilogue pattern): wave stages its x row in
// LDS once, then 16 broadcast ds_read_b128 + coalesced W row loads feed
// two pk_fma chains — replaces 64 serial ds_bpermute round-trips.
__global__ __launch_bounds__(256) void k_transform1(
    const float* __restrict__ x, const float* __restrict__ Wl,
    const float* __restrict__ Wr, unsigned short* __restrict__ xlb,
    float* __restrict__ xr) {
  __shared__ __align__(16) float rv[4][64];
  int wid = (int)((blockIdx.x * blockDim.x + threadIdx.x) >> 6);
  int lane = threadIdx.x & 63;
  int wv = (threadIdx.x >> 6) & 3;
  if (wid >= N_NODES) return;
  float xv = x[wid * 64 + lane];
  rv[wv][lane] = xv;
  asm volatile("s_waitcnt lgkmcnt(0)" ::: "memory");   // same-wave LDS drain
  const float* W = (lane < 32) ? Wl : Wr;
  int c = lane & 31;
  v2f s0 = {0.f, 0.f}, s1 = {0.f, 0.f};
#pragma unroll
  for (int k = 0; k < 64; k += 4) {
    float4 r = *(const float4*)&rv[wv][k];
    v2f w0; w0.x = W[(k + 0) * 32 + c]; w0.y = W[(k + 1) * 32 + c];
    v2f w1; w1.x = W[(k + 2) * 32 + c]; w1.y = W[(k + 3) * 32 + c];
    v2f p0; p0.x = r.x; p0.y = r.y;
    v2f p1; p1.x = r.z; p1.y = r.w;
    s0 += p0 * w0;                     // v_pk_fma_f32
    s1 += p1 * w1;
  }
  float s = (s0.x + s0.y) + (s1.x + s1.y);
  if (lane < 32) xlb[wid * 32 + c] = f2bf(s);
  else           xr[wid * 32 + c] = s;
}

// ------ Pass A: LDS-staged partition by coarse cell (dst>>11), 49 cells ---
__global__ __launch_bounds__(256) void k_binA(
    const int* __restrict__ src, const int* __restrict__ dst,
    int* __restrict__ curA, unsigned* __restrict__ bufA) {
  __shared__ int hist[NCC];
  __shared__ int offsL[NCC + 1];
  __shared__ int baseL[NCC];
  __shared__ int place[NCC];
  __shared__ unsigned stag[2048];
  __shared__ unsigned char cellb[2048];
  int t = threadIdx.x;
  for (long long start = (long long)blockIdx.x * 2048; start < N_EDGES;
       start += (long long)gridDim.x * 2048) {
    int n = (int)min((long long)2048, (long long)N_EDGES - start);
    for (int i = t; i < NCC; i += 256) hist[i] = 0;
    __syncthreads();
    unsigned pv[8]; int pc[8];
#pragma unroll
    for (int i = 0; i < 8; ++i) {
      int idx = t + i * 256;
      if (idx < n) {
        int d = dst[start + idx];
        int s = src[start + idx];
        int cc = d >> 11;
        pc[i] = cc;
        pv[i] = (unsigned)s | ((unsigned)(d & 2047) << 17);
        atomicAdd(&hist[cc], 1);
      } else pc[i] = -1;
    }
    __syncthreads();
    if (t < 64) {
      int lane = t;
      int v = (lane < NCC) ? hist[lane] : 0;
      int x = v;
#pragma unroll
      for (int o = 1; o < 64; o <<= 1) {
        int y = __shfl_up(x, o, 64);
        if (lane >= o) x += y;
      }
      if (lane < NCC) {
        offsL[lane] = x - v;
        place[lane] = 0;
        if (v > 0) baseL[lane] = atomicAdd(&curA[lane], v);
      }
      if (lane == NCC - 1) offsL[NCC] = x;
    }
    __syncthreads();
#pragma unroll
    for (int i = 0; i < 8; ++i) {
      if (pc[i] >= 0) {
        int p = atomicAdd(&place[pc[i]], 1);
        int sl = offsL[pc[i]] + p;
        stag[sl] = pv[i];
        cellb[sl] = (unsigned char)pc[i];
      }
    }
    __syncthreads();
    for (int s2 = t; s2 < n; s2 += 256) {     // coalesced copy-out, no search
      int cell = cellb[s2];
      int pos = baseL[cell] + (s2 - offsL[cell]);
      if (pos < CAPA) bufA[(size_t)cell * CAPA + pos] = stag[s2];
    }
    __syncthreads();
  }
}

// ------ Pass B: refine each coarse cell into 64 fine buckets -------------
__global__ __launch_bounds__(256) void k_binB(
    const unsigned* __restrict__ bufA, const int* __restrict__ curA,
    int* __restrict__ cur, unsigned* __restrict__ buf) {
  __shared__ int hist[NFB];
  __shared__ int offsL[NFB + 1];
  __shared__ int baseL[NFB];
  __shared__ int place[NFB];
  __shared__ unsigned stag[2048];
  __shared__ unsigned char cellb[2048];
  int cellc = blockIdx.x / BPC;
  int slice = blockIdx.x % BPC;
  int t = threadIdx.x;
  int cnt = min(curA[cellc], CAPA);
  const unsigned* in = bufA + (size_t)cellc * CAPA;
  for (int start = slice * 2048; start < cnt; start += BPC * 2048) {
    int n = min(2048, cnt - start);
    for (int i = t; i < NFB; i += 256) hist[i] = 0;
    __syncthreads();
    unsigned pv[8]; int pb[8];
#pragma unroll
    for (int i = 0; i < 8; ++i) {
      int idx = t + i * 256;
      if (idx < n) {
        unsigned w = in[start + idx];
        int dlow = (int)(w >> 17);
        int fb = dlow >> 5;
        pb[i] = fb;
        pv[i] = (w & 0x1FFFFu) | ((unsigned)(dlow & 31) << 17);
        atomicAdd(&hist[fb], 1);
      } else pb[i] = -1;
    }
    __syncthreads();
    if (t < 64) {
      int lane = t;
      int v = hist[lane];
      int x = v;
#pragma unroll
      for (int o = 1; o < 64; o <<= 1) {
        int y = __shfl_up(x, o, 64);
        if (lane >= o) x += y;
      }
      offsL[lane] = x - v;
      place[lane] = 0;
      if (v > 0) baseL[lane] = atomicAdd(&cur[cellc * NFB + lane], v);
      if (lane == 63) offsL[NFB] = x;
    }
    __syncthreads();
#pragma unroll
    for (int i = 0; i < 8; ++i) {
      if (pb[i] >= 0) {
        int p = atomicAdd(&place[pb[i]], 1);
        int sl = offsL[pb[i]] + p;
        stag[sl] = pv[i];
        cellb[sl] = (unsigned char)pb[i];
      }
    }
    __syncthreads();
    for (int s2 = t; s2 < n; s2 += 256) {
      int fb = cellb[s2];
      int pos = baseL[fb] + (s2 - offsL[fb]);
      if (pos < CAP) buf[(size_t)(cellc * NFB + fb) * CAP + pos] = stag[s2];
    }
    __syncthreads();
  }
}

// --------- single-block exclusive scan of bucket totals -> bbase ----------
__global__ __launch_bounds__(1024) void k_bscan(
    const int* __restrict__ cur, int* __restrict__ bbase) {
  __shared__ int warp_sums[16];
  __shared__ int s_running;
  int t = threadIdx.x;
  int lane = t & 63, w = t >> 6;
  if (t == 0) s_running = 0;
  __syncthreads();
  for (int base = 0; base < NB; base += 1024) {
    int i = base + t;
    int v = (i < NB) ? min(cur[i], CAP) : 0;
    int x = v;
#pragma unroll
    for (int o = 1; o < 64; o <<= 1) {
      int y = __shfl_up(x, o, 64);
      if (lane >= o) x += y;
    }
    if (lane == 63) warp_sums[w] = x;
    __syncthreads();
    if (w == 0) {
      int ws = (lane < 16) ? warp_sums[lane] : 0;
#pragma unroll
      for (int o = 1; o < 16; o <<= 1) {
        int y = __shfl_up(ws, o, 64);
        if (lane >= o) ws += y;
      }
      if (lane < 16) warp_sums[lane] = ws;
    }
    __syncthreads();
    int incl = x + (w > 0 ? warp_sums[w - 1] : 0);
    int excl = s_running + incl - v;
    if (i < NB) bbase[i] = excl;
    __syncthreads();
    if (t == 1023) s_running += incl;
    __syncthreads();
  }
}

// ------ block per bucket: LDS-staged count + prefix, dense CSR fill -------
__global__ __launch_bounds__(256) void k_bfill(
    const unsigned* __restrict__ buf, const int* __restrict__ cur,
    const int* __restrict__ bbase, int* __restrict__ deg,
    int* __restrict__ offs, int* __restrict__ eidx) {
  __shared__ int ncnt[NPB];
  __shared__ int ncur[NPB];
  __shared__ unsigned sbuf[CAP];
  int b = blockIdx.x, t = threadIdx.x;
  if (t < NPB) ncnt[t] = 0;
  __syncthreads();
  int nb = min(cur[b], CAP);
  const unsigned* bb = buf + (size_t)b * CAP;
  for (int slot = t; slot < nb; slot += 256) {
    unsigned w = bb[slot];
    sbuf[slot] = w;
    atomicAdd(&ncnt[w >> 17], 1);
  }
  __syncthreads();
  if (t < 64) {
    int lane = t;
    int c = (lane < NPB) ? ncnt[lane] : 0;
    int x = c;
#pragma unroll
    for (int o = 1; o < 32; o <<= 1) {
      int y = __shfl_up(x, o, 64);
      if (lane >= o) x += y;
    }
    if (lane < NPB) {
      int excl = x - c;
      ncur[lane] = excl;
      int gn = b * NPB + lane;
      deg[gn] = c;
      offs[gn] = bbase[b] + excl;
    }
  }
  __syncthreads();
  int base = bbase[b];
  for (int slot = t; slot < nb; slot += 256) {
    unsigned w = sbuf[slot];
    int p = atomicAdd(&ncur[w >> 17], 1);
    eidx[base + p] = (int)(w & 0x1FFFF);
  }
}

// ---- Gather layer 1: hp = bf16(dropout(lrelu(mean(xl[nbrs])+b1+xr))) ----
__global__ __launch_bounds__(256) void k_gather1(
    const unsigned short* __restrict__ xlb, const float* __restrict__ xr,
    const int* __restrict__ offs, const int* __restrict__ deg,
    const int* __restrict__ eidx, const float* __restrict__ b1,
    unsigned short* __restrict__ hpb) {
  int wid = (int)((blockIdx.x * blockDim.x + threadIdx.x) >> 6);
  int lane = threadIdx.x & 63;
  if (wid >= N_NODES) return;
  int g = lane >> 3, ch = lane & 7;
  int off = offs[wid];
  int dg = deg[wid];
  // hoisted tail operands: in flight during the gather loop
  int c32 = lane & 31;
  float xr_v = xr[wid * 32 + c32];
  float b1_v = b1[c32];
  const uint2* x2 = (const uint2*)xlb;
  v2f acc01 = {0.f, 0.f}, acc23 = {0.f, 0.f};
  int k = 0;
  for (; k + 16 <= dg; k += 16) {
    int s0 = eidx[off + k + g];
    int s1 = eidx[off + k + 8 + g];
    uint2 r0 = x2[s0 * 8 + ch];
    uint2 r1 = x2[s1 * 8 + ch];
    acc01 += up2(r0.x); acc23 += up2(r0.y);
    acc01 += up2(r1.x); acc23 += up2(r1.y);
  }
  for (; k < dg; k += 8) {
    if (k + g < dg) {
      int s = eidx[off + k + g];
      uint2 r = x2[s * 8 + ch];
      acc01 += up2(r.x); acc23 += up2(r.y);
    }
  }
  float a0 = acc01.x, a1 = acc01.y, a2 = acc23.x, a3 = acc23.y;
  a0 += __shfl_xor(a0, 8, 64); a0 += __shfl_xor(a0, 16, 64); a0 += __shfl_xor(a0, 32, 64);
  a1 += __shfl_xor(a1, 8, 64); a1 += __shfl_xor(a1, 16, 64); a1 += __shfl_xor(a1, 32, 64);
  a2 += __shfl_xor(a2, 8, 64); a2 += __shfl_xor(a2, 16, 64); a2 += __shfl_xor(a2, 32, 64);
  a3 += __shfl_xor(a3, 8, 64); a3 += __shfl_xor(a3, 16, 64); a3 += __shfl_xor(a3, 32, 64);
  int chunk = lane >> 2, sub = lane & 3;
  float t0 = __shfl(a0, chunk, 64);
  float t1 = __shfl(a1, chunk, 64);
  float t2 = __shfl(a2, chunk, 64);
  float t3 = __shfl(a3, chunk, 64);
  float val = (sub == 0) ? t0 : (sub == 1) ? t1 : (sub == 2) ? t2 : t3;
  if (lane < 32) {
    float inv = 1.0f / fmaxf((float)dg, 1.0f);
    int j = wid * 32 + lane;
    float v = val * inv + b1_v + xr_v;
    v = (v > 0.f) ? v : 0.01f * v;
    float h = keep_bit(DK0.a, DK0.b, (unsigned)j) ? 2.0f * v : 0.0f;
    hpb[j] = f2bf(h);
  }
}

// ---- Gather layer 2 + LDS-broadcast GEMM (pk_fma) + dropout + L2 norm ---
__global__ __launch_bounds__(256) void k_out(
    const unsigned short* __restrict__ hpb, const int* __restrict__ offs,
    const int* __restrict__ deg, const int* __restrict__ eidx,
    const float* __restrict__ W2l, const float* __restrict__ b2,
    const float* __restrict__ W2r, float* __restrict__ out) {
  __shared__ __align__(16) float rv[4][64];
  int wid = (int)((blockIdx.x * blockDim.x + threadIdx.x) >> 6);
  int lane = threadIdx.x & 63;
  int wv = (threadIdx.x >> 6) & 3;
  if (wid >= N_NODES) return;
  int g = lane >> 3, ch = lane & 7;
  int off = offs[wid];
  int dg = deg[wid];
  const uint2* h2 = (const uint2*)hpb;
  // hoisted: own hp-row chunk (one 64B line/wave) + bias, in flight during gather
  uint2 own = h2[wid * 8 + ch];
  float bias = b2[lane];
  v2f acc01 = {0.f, 0.f}, acc23 = {0.f, 0.f};
  int k = 0;
  for (; k + 16 <= dg; k += 16) {
    int s0 = eidx[off + k + g];
    int s1 = eidx[off + k + 8 + g];
    uint2 r0 = h2[s0 * 8 + ch];
    uint2 r1 = h2[s1 * 8 + ch];
    acc01 += up2(r0.x); acc23 += up2(r0.y);
    acc01 += up2(r1.x); acc23 += up2(r1.y);
  }
  for (; k < dg; k += 8) {
    if (k + g < dg) {
      int s = eidx[off + k + g];
      uint2 r = h2[s * 8 + ch];
      acc01 += up2(r.x); acc23 += up2(r.y);
    }
  }
  float a0 = acc01.x, a1 = acc01.y, a2 = acc23.x, a3 = acc23.y;
  a0 += __shfl_xor(a0, 8, 64); a0 += __shfl_xor(a0, 16, 64); a0 += __shfl_xor(a0, 32, 64);
  a1 += __shfl_xor(a1, 8, 64); a1 += __shfl_xor(a1, 16, 64); a1 += __shfl_xor(a1, 32, 64);
  a2 += __shfl_xor(a2, 8, 64); a2 += __shfl_xor(a2, 16, 64); a2 += __shfl_xor(a2, 32, 64);
  a3 += __shfl_xor(a3, 8, 64); a3 += __shfl_xor(a3, 16, 64); a3 += __shfl_xor(a3, 32, 64);
  float inv = 1.0f / fmaxf((float)dg, 1.0f);
  if (lane < 8) {                     // mean-agg row, cols 4*lane..4*lane+3
    float4 v;
    v.x = a0 * inv; v.y = a1 * inv; v.z = a2 * inv; v.w = a3 * inv;
    *(float4*)&rv[wv][lane * 4] = v;
  } else if (lane < 16) {             // own hp row (ch == lane-8 here)
    float4 v;
    v.x = __uint_as_float(own.x << 16);
    v.y = __uint_as_float(own.x & 0xFFFF0000u);
    v.z = __uint_as_float(own.y << 16);
    v.w = __uint_as_float(own.y & 0xFFFF0000u);
    *(float4*)&rv[wv][32 + (lane - 8) * 4] = v;
  }
  asm volatile("s_waitcnt lgkmcnt(0)" ::: "memory");   // same-wave LDS drain
  v2f sa = {0.f, 0.f}, sb = {0.f, 0.f};
#pragma unroll
  for (int kk = 0; kk < 32; kk += 4) {
    float4 r1 = *(const float4*)&rv[wv][kk];
    float4 r2 = *(const float4*)&rv[wv][32 + kk];
    v2f w0; w0.x = W2l[(kk + 0) * 64 + lane]; w0.y = W2l[(kk + 1) * 64 + lane];
    v2f w1; w1.x = W2l[(kk + 2) * 64 + lane]; w1.y = W2l[(kk + 3) * 64 + lane];
    v2f u0; u0.x = W2r[(kk + 0) * 64 + lane]; u0.y = W2r[(kk + 1) * 64 + lane];
    v2f u1; u1.x = W2r[(kk + 2) * 64 + lane]; u1.y = W2r[(kk + 3) * 64 + lane];
    v2f p0; p0.x = r1.x; p0.y = r1.y;
    v2f p1; p1.x = r1.z; p1.y = r1.w;
    v2f q0; q0.x = r2.x; q0.y = r2.y;
    v2f q1; q1.x = r2.z; q1.y = r2.w;
    sa += p0 * w0;  sa += p1 * w1;    // v_pk_fma_f32
    sb += q0 * u0;  sb += q1 * u1;
  }
  float v = (sa.x + sa.y) + (sb.x + sb.y) + bias;
  unsigned j = (unsigned)(wid * 64 + lane);
  float d = keep_bit(DK1.a, DK1.b, j) ? 2.0f * v : 0.0f;
  float ss = d * d;
#pragma unroll
  for (int o = 32; o > 0; o >>= 1) ss += __shfl_xor(ss, o, 64);
  float scale = 1.0f / fmaxf(sqrtf(ss), 1e-12f);
  out[j] = d * scale;
}

// --------------------------------------------------------------------------
extern "C" void kernel_launch(void* const* d_in, const int* in_sizes, int n_in,
                              void* d_out, int out_size, void* d_ws, size_t ws_size,
                              hipStream_t stream) {
  const float* x   = (const float*)d_in[0];
  const int*   ei  = (const int*)d_in[1];
  const float* W1l = (const float*)d_in[2];
  const float* b1  = (const float*)d_in[3];
  const float* W1r = (const float*)d_in[4];
  const float* W2l = (const float*)d_in[5];
  const float* b2  = (const float*)d_in[6];
  const float* W2r = (const float*)d_in[7];
  float* out = (float*)d_out;

  const int* src = ei;            // edge_index[0]
  const int* dst = ei + N_EDGES;  // edge_index[1]

  const size_t F32 = (size_t)N_NODES * 32;
  char* w = (char*)d_ws;
  // region 1 (12.8 MB): bufA (passes A/B) then xr (transform onward)
  unsigned* bufA = (unsigned*)w;                 // 49*34816*4 = 6.8 MB
  float* xr      = (float*)w;                    // 12.8 MB (bufA dead by then)
  w += F32 * sizeof(float);
  // region 2 (12.8 MB): buf (passes B/bfill) then xlb+hpb (transform onward)
  unsigned* buf  = (unsigned*)w;                 // 3125*704*4 = 8.8 MB
  unsigned short* xlb = (unsigned short*)w;      // 6.4 MB
  unsigned short* hpb = xlb + F32;               // 6.4 MB (buf dead by then)
  w += F32 * 2 * sizeof(unsigned short);
  int* curA  = (int*)w; w += NCC * sizeof(int);
  int* cur   = (int*)w; w += NB * sizeof(int);
  int* bbase = (int*)w; w += NB * sizeof(int);
  int* deg   = (int*)w; w += N_NODES * sizeof(int);
  int* offs  = (int*)w; w += N_NODES * sizeof(int);
  int* eidx  = (int*)w;                          // 6.4 MB (dense)

  hipMemsetAsync(curA, 0, (size_t)(NCC + NB) * sizeof(int), stream);

  k_binA<<<(N_EDGES + 2047) / 2048, 256, 0, stream>>>(src, dst, curA, bufA);
  k_binB<<<NCC * BPC, 256, 0, stream>>>(bufA, curA, cur, buf);
  k_bscan<<<1, 1024, 0, stream>>>(cur, bbase);
  k_bfill<<<NB, 256, 0, stream>>>(buf, cur, bbase, deg, offs, eidx);

  k_transform1<<<(N_NODES + 3) / 4, 256, 0, stream>>>(x, W1l, W1r, xlb, xr);
  k_gather1<<<(N_NODES + 3) / 4, 256, 0, stream>>>(xlb, xr, offs, deg, eidx, b1, hpb);
  k_out<<<(N_NODES + 3) / 4, 256, 0, stream>>>(hpb, offs, deg, eidx, W2l, b2, W2r, out);
}

// Round 16
// 283.264 us; speedup vs baseline: 1.1788x; 1.0413x over previous
//
#include <hip/hip_runtime.h>

#define N_NODES 100000
#define N_EDGES 1600000
#define NPB 32                       // nodes per bucket (dst >> 5)
#define NB (N_NODES / NPB)           // 3125 buckets
#define CAP 704                      // slots per bucket (mean 512 + 8.5 sigma)
#define NCC 49                       // coarse cells (dst >> 11)
#define CAPA 34816                   // slots per coarse cell (mean 32768 + 11 sigma)
#define NFB 64                       // fine buckets per coarse cell
#define BPC 16                       // blocks per cell in pass B

typedef float v2f __attribute__((ext_vector_type(2)));

// ---------------- JAX threefry2x32 (partitionable scheme) ----------------
struct U2 { unsigned a, b; };

__host__ __device__ constexpr U2 tf2x32(unsigned k0, unsigned k1, unsigned c0, unsigned c1) {
  unsigned ks2 = k0 ^ k1 ^ 0x1BD11BDAu;
  unsigned x0 = c0 + k0, x1 = c1 + k1;
#define TFR(r) { x0 += x1; x1 = (x1 << (r)) | (x1 >> (32 - (r))); x1 ^= x0; }
  TFR(13) TFR(15) TFR(26) TFR(6)
  x0 += k1;  x1 += ks2 + 1u;
  TFR(17) TFR(29) TFR(16) TFR(24)
  x0 += ks2; x1 += k0 + 2u;
  TFR(13) TFR(15) TFR(26) TFR(6)
  x0 += k0;  x1 += k1 + 3u;
  TFR(17) TFR(29) TFR(16) TFR(24)
  x0 += k1;  x1 += ks2 + 4u;
  TFR(13) TFR(15) TFR(26) TFR(6)
  x0 += ks2; x1 += k0 + 5u;
#undef TFR
  return U2{x0, x1};
}

constexpr U2 DK0 = tf2x32(0u, 42u, 0u, 0u);
constexpr U2 DK1 = tf2x32(0u, 42u, 0u, 1u);

__device__ __forceinline__ bool keep_bit(unsigned k0, unsigned k1, unsigned j) {
  U2 w = tf2x32(k0, k1, 0u, j);
  return ((w.a ^ w.b) >> 31) == 0u;
}

// bf16 storage helpers (RNE pack, shift unpack)
__device__ __forceinline__ unsigned short f2bf(float f) {
  unsigned u = __float_as_uint(f);
  u += 0x7FFFu + ((u >> 16) & 1u);
  return (unsigned short)(u >> 16);
}
// unpack uint32 (2 bf16) -> v2f
__device__ __forceinline__ v2f up2(unsigned r) {
  v2f v;
  v.x = __uint_as_float(r << 16);
  v.y = __uint_as_float(r & 0xFFFF0000u);
  return v;
}

// ------ Kernel A: xl = bf16(x@W1_l), xr = x@W1_r ------------------------
// LDS-broadcast GEMM: wave stages its x row in LDS once, then broadcast
// ds_read_b128 + coalesced W row loads feed two pk_fma chains.
__global__ __launch_bounds__(256) void k_transform1(
    const float* __restrict__ x, const float* __restrict__ Wl,
    const float* __restrict__ Wr, unsigned short* __restrict__ xlb,
    float* __restrict__ xr) {
  __shared__ __align__(16) float rv[4][64];
  int wid = (int)((blockIdx.x * blockDim.x + threadIdx.x) >> 6);
  int lane = threadIdx.x & 63;
  int wv = (threadIdx.x >> 6) & 3;
  if (wid >= N_NODES) return;
  float xv = x[wid * 64 + lane];
  rv[wv][lane] = xv;
  asm volatile("s_waitcnt lgkmcnt(0)" ::: "memory");   // same-wave LDS drain
  const float* W = (lane < 32) ? Wl : Wr;
  int c = lane & 31;
  v2f s0 = {0.f, 0.f}, s1 = {0.f, 0.f};
#pragma unroll
  for (int k = 0; k < 64; k += 4) {
    float4 r = *(const float4*)&rv[wv][k];
    v2f w0; w0.x = W[(k + 0) * 32 + c]; w0.y = W[(k + 1) * 32 + c];
    v2f w1; w1.x = W[(k + 2) * 32 + c]; w1.y = W[(k + 3) * 32 + c];
    v2f p0; p0.x = r.x; p0.y = r.y;
    v2f p1; p1.x = r.z; p1.y = r.w;
    s0 += p0 * w0;                     // v_pk_fma_f32
    s1 += p1 * w1;
  }
  float s = (s0.x + s0.y) + (s1.x + s1.y);
  if (lane < 32) xlb[wid * 32 + c] = f2bf(s);
  else           xr[wid * 32 + c] = s;
}

// ------ Pass A: LDS-staged partition by coarse cell (dst>>11), 49 cells ---
__global__ __launch_bounds__(256) void k_binA(
    const int* __restrict__ src, const int* __restrict__ dst,
    int* __restrict__ curA, unsigned* __restrict__ bufA) {
  __shared__ int hist[NCC];
  __shared__ int offsL[NCC + 1];
  __shared__ int baseL[NCC];
  __shared__ int place[NCC];
  __shared__ unsigned stag[2048];
  __shared__ unsigned char cellb[2048];
  int t = threadIdx.x;
  for (long long start = (long long)blockIdx.x * 2048; start < N_EDGES;
       start += (long long)gridDim.x * 2048) {
    int n = (int)min((long long)2048, (long long)N_EDGES - start);
    for (int i = t; i < NCC; i += 256) hist[i] = 0;
    __syncthreads();
    unsigned pv[8]; int pc[8];
#pragma unroll
    for (int i = 0; i < 8; ++i) {
      int idx = t + i * 256;
      if (idx < n) {
        int d = dst[start + idx];
        int s = src[start + idx];
        int cc = d >> 11;
        pc[i] = cc;
        pv[i] = (unsigned)s | ((unsigned)(d & 2047) << 17);
        atomicAdd(&hist[cc], 1);
      } else pc[i] = -1;
    }
    __syncthreads();
    if (t < 64) {
      int lane = t;
      int v = (lane < NCC) ? hist[lane] : 0;
      int x = v;
#pragma unroll
      for (int o = 1; o < 64; o <<= 1) {
        int y = __shfl_up(x, o, 64);
        if (lane >= o) x += y;
      }
      if (lane < NCC) {
        offsL[lane] = x - v;
        place[lane] = 0;
        if (v > 0) baseL[lane] = atomicAdd(&curA[lane], v);
      }
      if (lane == NCC - 1) offsL[NCC] = x;
    }
    __syncthreads();
#pragma unroll
    for (int i = 0; i < 8; ++i) {
      if (pc[i] >= 0) {
        int p = atomicAdd(&place[pc[i]], 1);
        int sl = offsL[pc[i]] + p;
        stag[sl] = pv[i];
        cellb[sl] = (unsigned char)pc[i];
      }
    }
    __syncthreads();
    for (int s2 = t; s2 < n; s2 += 256) {     // coalesced copy-out, no search
      int cell = cellb[s2];
      int pos = baseL[cell] + (s2 - offsL[cell]);
      if (pos < CAPA) bufA[(size_t)cell * CAPA + pos] = stag[s2];
    }
    __syncthreads();
  }
}

// ------ Pass B: refine each coarse cell into 64 fine buckets -------------
__global__ __launch_bounds__(256) void k_binB(
    const unsigned* __restrict__ bufA, const int* __restrict__ curA,
    int* __restrict__ cur, unsigned* __restrict__ buf) {
  __shared__ int hist[NFB];
  __shared__ int offsL[NFB + 1];
  __shared__ int baseL[NFB];
  __shared__ int place[NFB];
  __shared__ unsigned stag[2048];
  __shared__ unsigned char cellb[2048];
  int cellc = blockIdx.x / BPC;
  int slice = blockIdx.x % BPC;
  int t = threadIdx.x;
  int cnt = min(curA[cellc], CAPA);
  const unsigned* in = bufA + (size_t)cellc * CAPA;
  for (int start = slice * 2048; start < cnt; start += BPC * 2048) {
    int n = min(2048, cnt - start);
    for (int i = t; i < NFB; i += 256) hist[i] = 0;
    __syncthreads();
    unsigned pv[8]; int pb[8];
#pragma unroll
    for (int i = 0; i < 8; ++i) {
      int idx = t + i * 256;
      if (idx < n) {
        unsigned w = in[start + idx];
        int dlow = (int)(w >> 17);
        int fb = dlow >> 5;
        pb[i] = fb;
        pv[i] = (w & 0x1FFFFu) | ((unsigned)(dlow & 31) << 17);
        atomicAdd(&hist[fb], 1);
      } else pb[i] = -1;
    }
    __syncthreads();
    if (t < 64) {
      int lane = t;
      int v = hist[lane];
      int x = v;
#pragma unroll
      for (int o = 1; o < 64; o <<= 1) {
        int y = __shfl_up(x, o, 64);
        if (lane >= o) x += y;
      }
      offsL[lane] = x - v;
      place[lane] = 0;
      if (v > 0) baseL[lane] = atomicAdd(&cur[cellc * NFB + lane], v);
      if (lane == 63) offsL[NFB] = x;
    }
    __syncthreads();
#pragma unroll
    for (int i = 0; i < 8; ++i) {
      if (pb[i] >= 0) {
        int p = atomicAdd(&place[pb[i]], 1);
        int sl = offsL[pb[i]] + p;
        stag[sl] = pv[i];
        cellb[sl] = (unsigned char)pb[i];
      }
    }
    __syncthreads();
    for (int s2 = t; s2 < n; s2 += 256) {
      int fb = cellb[s2];
      int pos = baseL[fb] + (s2 - offsL[fb]);
      if (pos < CAP) buf[(size_t)(cellc * NFB + fb) * CAP + pos] = stag[s2];
    }
    __syncthreads();
  }
}

// --------- single-block exclusive scan of bucket totals -> bbase ----------
__global__ __launch_bounds__(1024) void k_bscan(
    const int* __restrict__ cur, int* __restrict__ bbase) {
  __shared__ int warp_sums[16];
  __shared__ int s_running;
  int t = threadIdx.x;
  int lane = t & 63, w = t >> 6;
  if (t == 0) s_running = 0;
  __syncthreads();
  for (int base = 0; base < NB; base += 1024) {
    int i = base + t;
    int v = (i < NB) ? min(cur[i], CAP) : 0;
    int x = v;
#pragma unroll
    for (int o = 1; o < 64; o <<= 1) {
      int y = __shfl_up(x, o, 64);
      if (lane >= o) x += y;
    }
    if (lane == 63) warp_sums[w] = x;
    __syncthreads();
    if (w == 0) {
      int ws = (lane < 16) ? warp_sums[lane] : 0;
#pragma unroll
      for (int o = 1; o < 16; o <<= 1) {
        int y = __shfl_up(ws, o, 64);
        if (lane >= o) ws += y;
      }
      if (lane < 16) warp_sums[lane] = ws;
    }
    __syncthreads();
    int incl = x + (w > 0 ? warp_sums[w - 1] : 0);
    int excl = s_running + incl - v;
    if (i < NB) bbase[i] = excl;
    __syncthreads();
    if (t == 1023) s_running += incl;
    __syncthreads();
  }
}

// ------ block per bucket: LDS-staged count + prefix, dense CSR fill -------
__global__ __launch_bounds__(256) void k_bfill(
    const unsigned* __restrict__ buf, const int* __restrict__ cur,
    const int* __restrict__ bbase, int* __restrict__ deg,
    int* __restrict__ offs, int* __restrict__ eidx) {
  __shared__ int ncnt[NPB];
  __shared__ int ncur[NPB];
  __shared__ unsigned sbuf[CAP];
  int b = blockIdx.x, t = threadIdx.x;
  if (t < NPB) ncnt[t] = 0;
  __syncthreads();
  int nb = min(cur[b], CAP);
  const unsigned* bb = buf + (size_t)b * CAP;
  for (int slot = t; slot < nb; slot += 256) {
    unsigned w = bb[slot];
    sbuf[slot] = w;
    atomicAdd(&ncnt[w >> 17], 1);
  }
  __syncthreads();
  if (t < 64) {
    int lane = t;
    int c = (lane < NPB) ? ncnt[lane] : 0;
    int x = c;
#pragma unroll
    for (int o = 1; o < 32; o <<= 1) {
      int y = __shfl_up(x, o, 64);
      if (lane >= o) x += y;
    }
    if (lane < NPB) {
      int excl = x - c;
      ncur[lane] = excl;
      int gn = b * NPB + lane;
      deg[gn] = c;
      offs[gn] = bbase[b] + excl;
    }
  }
  __syncthreads();
  int base = bbase[b];
  for (int slot = t; slot < nb; slot += 256) {
    unsigned w = sbuf[slot];
    int p = atomicAdd(&ncur[w >> 17], 1);
    eidx[base + p] = (int)(w & 0x1FFFF);
  }
}

// ---- Gather layer 1: TWO nodes per wave --------------------------------
// Lanes 0..31 = node 2w, lanes 32..63 = node 2w+1. Within a half: 4 edge
// groups x 8 chunks. Halves per-node fixed costs (shuffles, threefry,
// epilogue) vs wave-per-node. No cross-lane ops inside divergent loops;
// reductions (xor 8,16) and redistribute stay within each half.
__global__ __launch_bounds__(256) void k_gather1(
    const unsigned short* __restrict__ xlb, const float* __restrict__ xr,
    const int* __restrict__ offs, const int* __restrict__ deg,
    const int* __restrict__ eidx, const float* __restrict__ b1,
    unsigned short* __restrict__ hpb) {
  int pair = (int)((blockIdx.x * blockDim.x + threadIdx.x) >> 6);
  int lane = threadIdx.x & 63;
  int half = lane >> 5;
  int node = pair * 2 + half;
  if (node >= N_NODES) return;
  int g = (lane >> 3) & 3;             // edge group within half: 0..3
  int ch = lane & 7;                   // 8B chunk: 0..7
  int c32 = lane & 31;
  int off = offs[node];
  int dg = deg[node];
  // hoisted tail operands
  float xr_v = xr[node * 32 + c32];
  float b1_v = b1[c32];
  const uint2* x2 = (const uint2*)xlb;
  v2f acc01 = {0.f, 0.f}, acc23 = {0.f, 0.f};
  int k = 0;
  for (; k + 8 <= dg; k += 8) {        // 8 edges/node/iter, 2 idx + 2 row loads
    int s0 = eidx[off + k + g];
    int s1 = eidx[off + k + 4 + g];
    uint2 r0 = x2[s0 * 8 + ch];
    uint2 r1 = x2[s1 * 8 + ch];
    acc01 += up2(r0.x); acc23 += up2(r0.y);
    acc01 += up2(r1.x); acc23 += up2(r1.y);
  }
  for (; k < dg; k += 4) {
    if (k + g < dg) {
      int s = eidx[off + k + g];
      uint2 r = x2[s * 8 + ch];
      acc01 += up2(r.x); acc23 += up2(r.y);
    }
  }
  float a0 = acc01.x, a1 = acc01.y, a2 = acc23.x, a3 = acc23.y;
  // reduce across the 4 groups (lane bits 3,4) — intra-half
  a0 += __shfl_xor(a0, 8, 64); a0 += __shfl_xor(a0, 16, 64);
  a1 += __shfl_xor(a1, 8, 64); a1 += __shfl_xor(a1, 16, 64);
  a2 += __shfl_xor(a2, 8, 64); a2 += __shfl_xor(a2, 16, 64);
  a3 += __shfl_xor(a3, 8, 64); a3 += __shfl_xor(a3, 16, 64);
  // redistribute: lane wants col c32 = chunk*4 + sub; source lane in same half
  int chunk = c32 >> 2, sub = lane & 3;
  int srcl = (half << 5) + chunk;      // (srcl & 7) == chunk, group 0 — reduced
  float t0 = __shfl(a0, srcl, 64);
  float t1 = __shfl(a1, srcl, 64);
  float t2 = __shfl(a2, srcl, 64);
  float t3 = __shfl(a3, srcl, 64);
  float val = (sub == 0) ? t0 : (sub == 1) ? t1 : (sub == 2) ? t2 : t3;
  float inv = 1.0f / fmaxf((float)dg, 1.0f);
  int j = node * 32 + c32;
  float v = val * inv + b1_v + xr_v;
  v = (v > 0.f) ? v : 0.01f * v;
  float h = keep_bit(DK0.a, DK0.b, (unsigned)j) ? 2.0f * v : 0.0f;
  hpb[j] = f2bf(h);                    // full-wave 128B contiguous store
}

// ---- Gather layer 2 + LDS-broadcast GEMM (pk_fma) + dropout + L2 norm ---
__global__ __launch_bounds__(256) void k_out(
    const unsigned short* __restrict__ hpb, const int* __restrict__ offs,
    const int* __restrict__ deg, const int* __restrict__ eidx,
    const float* __restrict__ W2l, const float* __restrict__ b2,
    const float* __restrict__ W2r, float* __restrict__ out) {
  __shared__ __align__(16) float rv[4][64];
  int wid = (int)((blockIdx.x * blockDim.x + threadIdx.x) >> 6);
  int lane = threadIdx.x & 63;
  int wv = (threadIdx.x >> 6) & 3;
  if (wid >= N_NODES) return;
  int g = lane >> 3, ch = lane & 7;
  int off = offs[wid];
  int dg = deg[wid];
  const uint2* h2 = (const uint2*)hpb;
  // hoisted: own hp-row chunk (one 64B line/wave) + bias, in flight during gather
  uint2 own = h2[wid * 8 + ch];
  float bias = b2[lane];
  v2f acc01 = {0.f, 0.f}, acc23 = {0.f, 0.f};
  int k = 0;
  for (; k + 16 <= dg; k += 16) {
    int s0 = eidx[off + k + g];
    int s1 = eidx[off + k + 8 + g];
    uint2 r0 = h2[s0 * 8 + ch];
    uint2 r1 = h2[s1 * 8 + ch];
    acc01 += up2(r0.x); acc23 += up2(r0.y);
    acc01 += up2(r1.x); acc23 += up2(r1.y);
  }
  for (; k < dg; k += 8) {
    if (k + g < dg) {
      int s = eidx[off + k + g];
      uint2 r = h2[s * 8 + ch];
      acc01 += up2(r.x); acc23 += up2(r.y);
    }
  }
  float a0 = acc01.x, a1 = acc01.y, a2 = acc23.x, a3 = acc23.y;
  a0 += __shfl_xor(a0, 8, 64); a0 += __shfl_xor(a0, 16, 64); a0 += __shfl_xor(a0, 32, 64);
  a1 += __shfl_xor(a1, 8, 64); a1 += __shfl_xor(a1, 16, 64); a1 += __shfl_xor(a1, 32, 64);
  a2 += __shfl_xor(a2, 8, 64); a2 += __shfl_xor(a2, 16, 64); a2 += __shfl_xor(a2, 32, 64);
  a3 += __shfl_xor(a3, 8, 64); a3 += __shfl_xor(a3, 16, 64); a3 += __shfl_xor(a3, 32, 64);
  float inv = 1.0f / fmaxf((float)dg, 1.0f);
  if (lane < 8) {                     // mean-agg row, cols 4*lane..4*lane+3
    float4 v;
    v.x = a0 * inv; v.y = a1 * inv; v.z = a2 * inv; v.w = a3 * inv;
    *(float4*)&rv[wv][lane * 4] = v;
  } else if (lane < 16) {             // own hp row (ch == lane-8 here)
    float4 v;
    v.x = __uint_as_float(own.x << 16);
    v.y = __uint_as_float(own.x & 0xFFFF0000u);
    v.z = __uint_as_float(own.y << 16);
    v.w = __uint_as_float(own.y & 0xFFFF0000u);
    *(float4*)&rv[wv][32 + (lane - 8) * 4] = v;
  }
  asm volatile("s_waitcnt lgkmcnt(0)" ::: "memory");   // same-wave LDS drain
  v2f sa = {0.f, 0.f}, sb = {0.f, 0.f};
#pragma unroll
  for (int kk = 0; kk < 32; kk += 4) {
    float4 r1 = *(const float4*)&rv[wv][kk];
    float4 r2 = *(const float4*)&rv[wv][32 + kk];
    v2f w0; w0.x = W2l[(kk + 0) * 64 + lane]; w0.y = W2l[(kk + 1) * 64 + lane];
    v2f w1; w1.x = W2l[(kk + 2) * 64 + lane]; w1.y = W2l[(kk + 3) * 64 + lane];
    v2f u0; u0.x = W2r[(kk + 0) * 64 + lane]; u0.y = W2r[(kk + 1) * 64 + lane];
    v2f u1; u1.x = W2r[(kk + 2) * 64 + lane]; u1.y = W2r[(kk + 3) * 64 + lane];
    v2f p0; p0.x = r1.x; p0.y = r1.y;
    v2f p1; p1.x = r1.z; p1.y = r1.w;
    v2f q0; q0.x = r2.x; q0.y = r2.y;
    v2f q1; q1.x = r2.z; q1.y = r2.w;
    sa += p0 * w0;  sa += p1 * w1;    // v_pk_fma_f32
    sb += q0 * u0;  sb += q1 * u1;
  }
  float v = (sa.x + sa.y) + (sb.x + sb.y) + bias;
  unsigned j = (unsigned)(wid * 64 + lane);
  float d = keep_bit(DK1.a, DK1.b, j) ? 2.0f * v : 0.0f;
  float ss = d * d;
#pragma unroll
  for (int o = 32; o > 0; o >>= 1) ss += __shfl_xor(ss, o, 64);
  float scale = 1.0f / fmaxf(sqrtf(ss), 1e-12f);
  out[j] = d * scale;
}

// --------------------------------------------------------------------------
extern "C" void kernel_launch(void* const* d_in, const int* in_sizes, int n_in,
                              void* d_out, int out_size, void* d_ws, size_t ws_size,
                              hipStream_t stream) {
  const float* x   = (const float*)d_in[0];
  const int*   ei  = (const int*)d_in[1];
  const float* W1l = (const float*)d_in[2];
  const float* b1  = (const float*)d_in[3];
  const float* W1r = (const float*)d_in[4];
  const float* W2l = (const float*)d_in[5];
  const float* b2  = (const float*)d_in[6];
  const float* W2r = (const float*)d_in[7];
  float* out = (float*)d_out;

  const int* src = ei;            // edge_index[0]
  const int* dst = ei + N_EDGES;  // edge_index[1]

  const size_t F32 = (size_t)N_NODES * 32;
  char* w = (char*)d_ws;
  // region 1 (12.8 MB): bufA (passes A/B) then xr (transform onward)
  unsigned* bufA = (unsigned*)w;                 // 49*34816*4 = 6.8 MB
  float* xr      = (float*)w;                    // 12.8 MB (bufA dead by then)
  w += F32 * sizeof(float);
  // region 2 (12.8 MB): buf (passes B/bfill) then xlb+hpb (transform onward)
  unsigned* buf  = (unsigned*)w;                 // 3125*704*4 = 8.8 MB
  unsigned short* xlb = (unsigned short*)w;      // 6.4 MB
  unsigned short* hpb = xlb + F32;               // 6.4 MB (buf dead by then)
  w += F32 * 2 * sizeof(unsigned short);
  int* curA  = (int*)w; w += NCC * sizeof(int);
  int* cur   = (int*)w; w += NB * sizeof(int);
  int* bbase = (int*)w; w += NB * sizeof(int);
  int* deg   = (int*)w; w += N_NODES * sizeof(int);
  int* offs  = (int*)w; w += N_NODES * sizeof(int);
  int* eidx  = (int*)w;                          // 6.4 MB (dense)

  hipMemsetAsync(curA, 0, (size_t)(NCC + NB) * sizeof(int), stream);

  k_binA<<<(N_EDGES + 2047) / 2048, 256, 0, stream>>>(src, dst, curA, bufA);
  k_binB<<<NCC * BPC, 256, 0, stream>>>(bufA, curA, cur, buf);
  k_bscan<<<1, 1024, 0, stream>>>(cur, bbase);
  k_bfill<<<NB, 256, 0, stream>>>(buf, cur, bbase, deg, offs, eidx);

  k_transform1<<<(N_NODES + 3) / 4, 256, 0, stream>>>(x, W1l, W1r, xlb, xr);
  k_gather1<<<(N_NODES / 2 + 3) / 4, 256, 0, stream>>>(xlb, xr, offs, deg, eidx, b1, hpb);
  k_out<<<(N_NODES + 3) / 4, 256, 0, stream>>>(hpb, offs, deg, eidx, W2l, b2, W2r, out);
}